// Round 26
// baseline (243.959 us; speedup 1.0000x reference)
//
#include <hip/hip_runtime.h>

// Problem sizes (match reference)
#define NS0 300000
#define ND0 50000
#define NE0 800000
#define NS1 50000
#define ND1 8192
#define NE1 131072
#define IN_F 256
#define HID_F 128
#define SLOTS 64    // bucket-CSR capacity; indeg ~ Poisson(16), P(>=64) ~ 1e-19
#define NT16 (NS0 / 16)   // 18750 16-row tiles
#define GEMM_GRID 2048
#define BUILD_GRID 512

typedef __attribute__((ext_vector_type(8))) _Float16 half8_t;
typedef __attribute__((ext_vector_type(4))) float f32x4;

// Workspace layout (4-byte words), all 16B-aligned:
#define OFF_OUTDEG0I 0
#define OFF_OUTDEG1I 300000
#define OFF_CNT0     350000
#define OFF_CNT1     400000
#define ZERO_WORDS   408192
#define OFF_EDGE0    408192
#define OFF_EDGE1    6808192
#define OFF_H1       7856768
#define OFF_W1T      14256768
#define OFF_G        14273152

// ---------------- init: blocks [0,128) zero counters; [128,160) cvt W1->w1t
__global__ __launch_bounds__(256) void k_init(
    int4* __restrict__ p, const float* __restrict__ W1,
    _Float16* __restrict__ w1t) {
  if (blockIdx.x < 128) {
    int i = blockIdx.x * 256 + threadIdx.x;
    for (; i < ZERO_WORDS / 4; i += 128 * 256) p[i] = make_int4(0, 0, 0, 0);
  } else {
    int i = (blockIdx.x - 128) * 256 + threadIdx.x;
    for (; i < IN_F * HID_F; i += 32 * 256) {
      int k = i >> 7, n = i & 127;
      w1t[n * 256 + k] = (_Float16)W1[i];
    }
  }
}

// ---------------- fused: blocks [0, BUILD_GRID) edge build (first dispatch
// wave -> overlaps); blocks [BUILD_GRID, +GEMM_GRID) dense GEMM g = x@W1.
// r26: T3+T4 schedule. Post-mortems r14/r17/r20/r24/r25: every pipelining
// attempt was defeated either by __syncthreads' vmcnt(0) drain or by the
// register-use stall at ds_write (wait happens at the USE, cover < latency).
// Fix = async global_load_lds (no register use) + COUNTED vmcnt(N) (never 0
// in the loop; FIFO semantics m135, tail-exact) + raw s_barrier (lgkm-only
// visibility; gld_lds completion is each wave's own vmcnt, checked before
// the barrier) + sched_barrier fences (rule 18). 3 LDS buffers, stage
// distance 3 -> ~2 tiles (~600-900cyc) of load cover. Fragment maps,
// source-swizzle, epilogue identical to the validated r24 kernel.
#define LDB(p, o) (*reinterpret_cast<const half8_t*>((p) + (o)))
__global__ __launch_bounds__(256) void k_gemm_build(
    const float* __restrict__ x, const _Float16* __restrict__ w1t,
    _Float16* __restrict__ g,
    const int* __restrict__ src0, const int* __restrict__ dst0,
    const float* __restrict__ ew0, int* __restrict__ outdeg0,
    int* __restrict__ cnt0, int2* __restrict__ edge0,
    const int* __restrict__ src1, const int* __restrict__ dst1,
    const float* __restrict__ ew1, int* __restrict__ outdeg1,
    int* __restrict__ cnt1, int2* __restrict__ edge1) {
  __shared__ __align__(16) float ldsA[3][16 * 256];   // 3 x 16KB f32
  __shared__ _Float16 ldsT[4][16 * 40];                // wave transpose, 5.1KB

  if (blockIdx.x < BUILD_GRID) {
    int tid = blockIdx.x * 256 + threadIdx.x;
    int stride = BUILD_GRID * 256;
    for (int i = tid; i < NE0; i += stride) {
      int s = src0[i];
      int d = dst0[i];
      float w = ew0[i];
      atomicAdd(&outdeg0[s], 1);
      int slot = atomicAdd(&cnt0[d], 1);
      if (slot < SLOTS) edge0[d * SLOTS + slot] = make_int2(s, __float_as_int(w));
    }
    for (int i = tid; i < NE1; i += stride) {
      int s = src1[i];
      int d = dst1[i];
      float w = ew1[i];
      atomicAdd(&outdeg1[s], 1);
      int slot = atomicAdd(&cnt1[d], 1);
      if (slot < SLOTS) edge1[d * SLOTS + slot] = make_int2(s, __float_as_int(w));
    }
    return;
  }

  // ---------------- GEMM path ----------------
  const int tid = threadIdx.x;
  const int wv = tid >> 6;
  const int lane = tid & 63;
  const int m = lane & 15;
  const int grp = lane >> 4;
  _Float16* tp = ldsT[wv];
  const int row_r = lane >> 2;   // epilogue: row 0..15
  const int q_r   = lane & 3;    // epilogue: 8-col quarter

  // B-frag: lane holds W1[k = kb*32 + grp*8 + j][n = 32wv + 16c + m]
  const _Float16* wb0 = w1t + (size_t)(32 * wv + m) * 256 + grp * 8;
  const _Float16* wb1 = wb0 + 16 * 256;
  const half8_t b00 = LDB(wb0, 0),   b01 = LDB(wb0, 32),  b02 = LDB(wb0, 64),
                b03 = LDB(wb0, 96),  b04 = LDB(wb0, 128), b05 = LDB(wb0, 160),
                b06 = LDB(wb0, 192), b07 = LDB(wb0, 224);
  const half8_t b10 = LDB(wb1, 0),   b11 = LDB(wb1, 32),  b12 = LDB(wb1, 64),
                b13 = LDB(wb1, 96),  b14 = LDB(wb1, 128), b15 = LDB(wb1, 160),
                b16 = LDB(wb1, 192), b17 = LDB(wb1, 224);

  const int bid = blockIdx.x - BUILD_GRID;

// issue 4 async 1KB row-loads for this wave (rows wv*4 .. wv*4+3);
// global source chunk = lane ^ (row&7) (involution; read applies same XOR)
#define STAGE(BUFI, T)                                                         \
  {                                                                            \
    const float* tb = x + (size_t)(T) * 4096;                                  \
    float* lb = &ldsA[BUFI][0];                                                \
    _Pragma("unroll") for (int r = 0; r < 4; ++r) {                            \
      const int mr = wv * 4 + r;                                               \
      const float* srcp = tb + mr * 256 + ((lane ^ (mr & 7)) << 2);            \
      __builtin_amdgcn_global_load_lds(                                        \
          (const __attribute__((address_space(1))) unsigned int*)srcp,         \
          (__attribute__((address_space(3))) unsigned int*)(lb + mr * 256),    \
          16, 0, 0);                                                           \
    }                                                                          \
  }

#define STEP(LB, KB, B0, B1)                                                   \
  {                                                                            \
    const int c0 = ((KB * 8 + grp * 2) ^ (m & 7)) << 2;                        \
    const int c1 = ((KB * 8 + grp * 2 + 1) ^ (m & 7)) << 2;                    \
    const f32x4 fa = *reinterpret_cast<const f32x4*>(LB + m * 256 + c0);       \
    const f32x4 fb = *reinterpret_cast<const f32x4*>(LB + m * 256 + c1);       \
    half8_t af;                                                                \
    af[0] = (_Float16)fa[0]; af[1] = (_Float16)fa[1];                          \
    af[2] = (_Float16)fa[2]; af[3] = (_Float16)fa[3];                          \
    af[4] = (_Float16)fb[0]; af[5] = (_Float16)fb[1];                          \
    af[6] = (_Float16)fb[2]; af[7] = (_Float16)fb[3];                          \
    acc0 = __builtin_amdgcn_mfma_f32_16x16x32_f16(af, B0, acc0, 0, 0, 0);      \
    acc1 = __builtin_amdgcn_mfma_f32_16x16x32_f16(af, B1, acc1, 0, 0, 0);      \
  }

// counted vmcnt wait (block-uniform immediate), then scheduling fence
#define WAITP(P)                                                               \
  do {                                                                         \
    switch (P) {                                                               \
      case 0: asm volatile("s_waitcnt vmcnt(0)"); break;                       \
      case 1: asm volatile("s_waitcnt vmcnt(1)"); break;                       \
      case 2: asm volatile("s_waitcnt vmcnt(2)"); break;                       \
      case 4: asm volatile("s_waitcnt vmcnt(4)"); break;                       \
      case 5: asm volatile("s_waitcnt vmcnt(5)"); break;                       \
      case 6: asm volatile("s_waitcnt vmcnt(6)"); break;                       \
      case 8: asm volatile("s_waitcnt vmcnt(8)"); break;                       \
      case 9: asm volatile("s_waitcnt vmcnt(9)"); break;                       \
      default: asm volatile("s_waitcnt vmcnt(10)"); break;                     \
    }                                                                          \
    __builtin_amdgcn_sched_barrier(0);                                         \
  } while (0)

  const int NTM = (NT16 - 1 - bid) / GEMM_GRID + 1;  // tiles this block owns
  int stages = (NTM < 3) ? NTM : 3;
  // prologue: stage up to 3 tiles into bufs 0..2
  for (int j = 0; j < stages; ++j) STAGE(j, bid + j * GEMM_GRID);

  for (int i = 0; i < NTM; ++i) {
    const int t = bid + i * GEMM_GRID;
    const int buf = i % 3;
    // ops issued after stage_i: 4 per newer stage + 1 store per iter since
    const int ns_after = stages - (i + 1);
    const int st_after = (i < 2) ? i : 2;
    WAITP(4 * ns_after + st_after);      // stage_i landed; newer stay in flight
    __builtin_amdgcn_s_barrier();        // all waves' stage_i landed (each
    __builtin_amdgcn_sched_barrier(0);   // checked its own vmcnt above)
    {
      const float* LB = &ldsA[buf][0];
      f32x4 acc0 = {0.f, 0.f, 0.f, 0.f};
      f32x4 acc1 = {0.f, 0.f, 0.f, 0.f};
      STEP(LB, 0, b00, b10)
      STEP(LB, 1, b01, b11)
      STEP(LB, 2, b02, b12)
      STEP(LB, 3, b03, b13)
      STEP(LB, 4, b04, b14)
      STEP(LB, 5, b05, b15)
      STEP(LB, 6, b06, b16)
      STEP(LB, 7, b07, b17)
      // epilogue: wave-private transpose patch -> coalesced g store
#pragma unroll
      for (int r = 0; r < 4; ++r) {
        tp[(4 * grp + r) * 40 + m]      = (_Float16)acc0[r];
        tp[(4 * grp + r) * 40 + 16 + m] = (_Float16)acc1[r];
      }
      const half8_t ov =
          *reinterpret_cast<const half8_t*>(tp + row_r * 40 + q_r * 8);
      *reinterpret_cast<half8_t*>(
          g + ((size_t)t * 16 + row_r) * 128 + 32 * wv + q_r * 8) = ov;
    }
    __builtin_amdgcn_sched_barrier(0);
    __builtin_amdgcn_s_barrier();        // all waves done READING buf
    __builtin_amdgcn_sched_barrier(0);
    const int tn = t + 3 * GEMM_GRID;    // refill the just-consumed buffer
    if (tn < NT16) {
      STAGE(buf, tn);
      ++stages;
    }
  }
#undef STAGE
#undef STEP
#undef WAITP
}

// ---------------- layer-1 aggregation over g (fp16, 77 MB, L3-resident):
// h1[d] = relu(rsqrt(indeg)*sum ew*rsqrt(outdeg0[src])*g[src] + b1) * rsqrt(outdeg1[d])
__global__ __launch_bounds__(256) void k_gather1(
    const _Float16* __restrict__ g, const int* __restrict__ cnt,
    const int2* __restrict__ edge, const int* __restrict__ outdeg0,
    const int* __restrict__ outdeg1, const float* __restrict__ b1,
    float* __restrict__ h1) {
  const int w = (blockIdx.x * 256 + threadIdx.x) >> 6;  // dst row
  const int lane = threadIdx.x & 63;
  const int gp = lane >> 4;
  const int sl = lane & 15;
  if (w >= ND0) return;
  const int deg = min(cnt[w], SLOTS);
  const int2* ep = edge + (size_t)w * SLOTS;
  float acc[8] = {0.f, 0.f, 0.f, 0.f, 0.f, 0.f, 0.f, 0.f};
  for (int e = 0; e < deg; e += 4) {
    const int idx = e + gp;
    int2 p = make_int2(0, 0);
    float c = 0.f;
    if (idx < deg) {
      p = ep[idx];
      c = __int_as_float(p.y) * rsqrtf(fmaxf((float)outdeg0[p.x], 1.0f));
    }
    const half8_t v =
        *reinterpret_cast<const half8_t*>(g + (size_t)p.x * 128 + sl * 8);
#pragma unroll
    for (int j = 0; j < 8; ++j) acc[j] = fmaf(c, (float)v[j], acc[j]);
  }
#pragma unroll
  for (int j = 0; j < 8; ++j) {
    acc[j] += __shfl_xor(acc[j], 16, 64);
    acc[j] += __shfl_xor(acc[j], 32, 64);
  }
  if (gp == 0) {
    const float sc = rsqrtf(fmaxf((float)deg, 1.0f));
    const float s1 = rsqrtf(fmaxf((float)outdeg1[w], 1.0f));
    const float4 bv0 = *reinterpret_cast<const float4*>(b1 + sl * 8);
    const float4 bv1 = *reinterpret_cast<const float4*>(b1 + sl * 8 + 4);
    float4 o0, o1;
    o0.x = fmaxf(fmaf(acc[0], sc, bv0.x), 0.0f) * s1;
    o0.y = fmaxf(fmaf(acc[1], sc, bv0.y), 0.0f) * s1;
    o0.z = fmaxf(fmaf(acc[2], sc, bv0.z), 0.0f) * s1;
    o0.w = fmaxf(fmaf(acc[3], sc, bv0.w), 0.0f) * s1;
    o1.x = fmaxf(fmaf(acc[4], sc, bv1.x), 0.0f) * s1;
    o1.y = fmaxf(fmaf(acc[5], sc, bv1.y), 0.0f) * s1;
    o1.z = fmaxf(fmaf(acc[6], sc, bv1.z), 0.0f) * s1;
    o1.w = fmaxf(fmaf(acc[7], sc, bv1.w), 0.0f) * s1;
    float* hr = h1 + (size_t)w * 128 + sl * 8;
    *reinterpret_cast<float4*>(hr) = o0;
    *reinterpret_cast<float4*>(hr + 4) = o1;
  }
}

#define FMA2(acc, c, v)        \
  acc.x = fmaf(c, v.x, acc.x); \
  acc.y = fmaf(c, v.y, acc.y);

// --------------------------------------------- fused gather + GEMM, layer 2
__global__ __launch_bounds__(256) void k_layer2(
    const float* __restrict__ h1, const int* __restrict__ cnt,
    const int2* __restrict__ edge, const float* __restrict__ W2,
    const float* __restrict__ b2, float* __restrict__ out) {
  __shared__ float arow[8][HID_F];
  const int t = blockIdx.x;
  const int wv = threadIdx.x >> 6;
  const int lane = threadIdx.x & 63;

#pragma unroll
  for (int rr = 0; rr < 2; ++rr) {
    const int row = t * 8 + wv * 2 + rr;
    const int deg = min(cnt[row], SLOTS);
    const int2* ep = edge + (size_t)row * SLOTS;
    float2 acc = make_float2(0.f, 0.f);
    int e = 0;
    for (; e + 4 <= deg; e += 4) {
      int4 q0 = *reinterpret_cast<const int4*>(ep + e);
      int4 q1 = *reinterpret_cast<const int4*>(ep + e + 2);
      float2 v0 = *reinterpret_cast<const float2*>(h1 + (size_t)q0.x * HID_F + lane * 2);
      float2 v1 = *reinterpret_cast<const float2*>(h1 + (size_t)q0.z * HID_F + lane * 2);
      float2 v2 = *reinterpret_cast<const float2*>(h1 + (size_t)q1.x * HID_F + lane * 2);
      float2 v3 = *reinterpret_cast<const float2*>(h1 + (size_t)q1.z * HID_F + lane * 2);
      FMA2(acc, __int_as_float(q0.y), v0);
      FMA2(acc, __int_as_float(q0.w), v1);
      FMA2(acc, __int_as_float(q1.y), v2);
      FMA2(acc, __int_as_float(q1.w), v3);
    }
    for (; e < deg; ++e) {
      int2 p = ep[e];
      float2 v = *reinterpret_cast<const float2*>(h1 + (size_t)p.x * HID_F + lane * 2);
      FMA2(acc, __int_as_float(p.y), v);
    }
    const float sc = rsqrtf(fmaxf((float)deg, 1.0f));
    *reinterpret_cast<float2*>(&arow[wv * 2 + rr][lane * 2]) =
        make_float2(acc.x * sc, acc.y * sc);
  }
  __syncthreads();

  const int j = threadIdx.x & 127;
  const int rg = threadIdx.x >> 7;
  float a0 = 0.f, a1 = 0.f, a2 = 0.f, a3 = 0.f;
  const float* wj = W2 + j;
#pragma unroll 8
  for (int k = 0; k < HID_F; ++k) {
    const float wvv = wj[(size_t)k * 128];
    a0 = fmaf(arow[rg * 4 + 0][k], wvv, a0);
    a1 = fmaf(arow[rg * 4 + 1][k], wvv, a1);
    a2 = fmaf(arow[rg * 4 + 2][k], wvv, a2);
    a3 = fmaf(arow[rg * 4 + 3][k], wvv, a3);
  }
  const float bj = b2[j];
  const int row0 = t * 8 + rg * 4;
  out[(size_t)(row0 + 0) * 128 + j] = fmaxf(a0 + bj, 0.0f);
  out[(size_t)(row0 + 1) * 128 + j] = fmaxf(a1 + bj, 0.0f);
  out[(size_t)(row0 + 2) * 128 + j] = fmaxf(a2 + bj, 0.0f);
  out[(size_t)(row0 + 3) * 128 + j] = fmaxf(a3 + bj, 0.0f);
}

extern "C" void kernel_launch(void* const* d_in, const int* in_sizes, int n_in,
                              void* d_out, int out_size, void* d_ws, size_t ws_size,
                              hipStream_t stream) {
  const float* x    = (const float*)d_in[0];
  const int*   src0 = (const int*)d_in[1];
  const int*   dst0 = (const int*)d_in[2];
  const float* ew0  = (const float*)d_in[3];
  const int*   src1 = (const int*)d_in[4];
  const int*   dst1 = (const int*)d_in[5];
  const float* ew1  = (const float*)d_in[6];
  const float* W1   = (const float*)d_in[7];
  const float* b1   = (const float*)d_in[8];
  const float* W2   = (const float*)d_in[9];
  const float* b2   = (const float*)d_in[10];
  float* out = (float*)d_out;

  int*   wsi = (int*)d_ws;
  float* wsf = (float*)d_ws;
  int* outdeg0 = wsi + OFF_OUTDEG0I;
  int* outdeg1 = wsi + OFF_OUTDEG1I;
  int* cnt0    = wsi + OFF_CNT0;
  int* cnt1    = wsi + OFF_CNT1;
  int2* edge0  = (int2*)(wsi + OFF_EDGE0);
  int2* edge1  = (int2*)(wsi + OFF_EDGE1);
  float* h1    = wsf + OFF_H1;
  _Float16* w1t = (_Float16*)(wsi + OFF_W1T);
  _Float16* g   = (_Float16*)(wsi + OFF_G);

  k_init<<<160, 256, 0, stream>>>((int4*)d_ws, W1, w1t);
  k_gemm_build<<<BUILD_GRID + GEMM_GRID, 256, 0, stream>>>(
      x, w1t, g, src0, dst0, ew0, outdeg0, cnt0, edge0,
      src1, dst1, ew1, outdeg1, cnt1, edge1);
  k_gather1<<<(ND0 * 64) / 256, 256, 0, stream>>>(g, cnt0, edge0, outdeg0,
                                                  outdeg1, b1, h1);
  k_layer2<<<ND1 / 8, 256, 0, stream>>>(h1, cnt1, edge1, W2, b2, out);
}

// Round 27
// 226.394 us; speedup vs baseline: 1.0776x; 1.0776x over previous
//
#include <hip/hip_runtime.h>

// Problem sizes (match reference)
#define NS0 300000
#define ND0 50000
#define NE0 800000
#define NS1 50000
#define ND1 8192
#define NE1 131072
#define IN_F 256
#define HID_F 128
#define SLOTS 64    // bucket-CSR capacity; indeg ~ Poisson(16), P(>=64) ~ 1e-19
#define NT16 (NS0 / 16)   // 18750 16-row tiles
#define GEMM_GRID 2048
#define BUILD_GRID 512

typedef __attribute__((ext_vector_type(8))) _Float16 half8_t;
typedef __attribute__((ext_vector_type(4))) float f32x4;

// Workspace layout (4-byte words), all 16B-aligned:
#define OFF_OUTDEG0I 0
#define OFF_OUTDEG1I 300000
#define OFF_CNT0     350000
#define OFF_CNT1     400000
#define ZERO_WORDS   408192
#define OFF_EDGE0    408192
#define OFF_EDGE1    6808192
#define OFF_H1       7856768
#define OFF_W1T      14256768
#define OFF_G        14273152

// ---------------- init: blocks [0,128) zero counters; [128,160) cvt W1->w1t
__global__ __launch_bounds__(256) void k_init(
    int4* __restrict__ p, const float* __restrict__ W1,
    _Float16* __restrict__ w1t) {
  if (blockIdx.x < 128) {
    int i = blockIdx.x * 256 + threadIdx.x;
    for (; i < ZERO_WORDS / 4; i += 128 * 256) p[i] = make_int4(0, 0, 0, 0);
  } else {
    int i = (blockIdx.x - 128) * 256 + threadIdx.x;
    for (; i < IN_F * HID_F; i += 32 * 256) {
      int k = i >> 7, n = i & 127;
      w1t[n * 256 + k] = (_Float16)W1[i];
    }
  }
}

// ---------------- fused: blocks [0, BUILD_GRID) edge build (first dispatch
// wave -> overlaps); blocks [BUILD_GRID, +GEMM_GRID) dense GEMM g = x@W1.
// CHAMPION (r24, 227.45us): async global_load_lds staging (width=16, no
// VGPR round-trip), LDS dest linear + source-swizzled (m173 involution:
// lane w of row r sources chunk w^(r&7); reader fetches (kb*8+grp*2+h)^(m&7)),
// cvt f32->fp16 at LDS read, one __syncthreads per tile (m97 pattern),
// build-first range fusion. Five alternative schedules falsified (r10 spill,
// r17 raw-barrier, r20 32-row, r25 occupancy, r26 counted-vmcnt) — this is
// the measured optimum of the single-x-read fused structure.
#define LDB(p, o) (*reinterpret_cast<const half8_t*>((p) + (o)))
__global__ __launch_bounds__(256) void k_gemm_build(
    const float* __restrict__ x, const _Float16* __restrict__ w1t,
    _Float16* __restrict__ g,
    const int* __restrict__ src0, const int* __restrict__ dst0,
    const float* __restrict__ ew0, int* __restrict__ outdeg0,
    int* __restrict__ cnt0, int2* __restrict__ edge0,
    const int* __restrict__ src1, const int* __restrict__ dst1,
    const float* __restrict__ ew1, int* __restrict__ outdeg1,
    int* __restrict__ cnt1, int2* __restrict__ edge1) {
  __shared__ __align__(16) float ldsA[2][16 * 256];   // 2 x 16KB f32
  __shared__ _Float16 ldsT[4][16 * 40];                // wave transpose, 5.1KB

  if (blockIdx.x < BUILD_GRID) {
    int tid = blockIdx.x * 256 + threadIdx.x;
    int stride = BUILD_GRID * 256;
    for (int i = tid; i < NE0; i += stride) {
      int s = src0[i];
      int d = dst0[i];
      float w = ew0[i];
      atomicAdd(&outdeg0[s], 1);
      int slot = atomicAdd(&cnt0[d], 1);
      if (slot < SLOTS) edge0[d * SLOTS + slot] = make_int2(s, __float_as_int(w));
    }
    for (int i = tid; i < NE1; i += stride) {
      int s = src1[i];
      int d = dst1[i];
      float w = ew1[i];
      atomicAdd(&outdeg1[s], 1);
      int slot = atomicAdd(&cnt1[d], 1);
      if (slot < SLOTS) edge1[d * SLOTS + slot] = make_int2(s, __float_as_int(w));
    }
    return;
  }

  // ---------------- GEMM path ----------------
  const int tid = threadIdx.x;
  const int wv = tid >> 6;
  const int lane = tid & 63;
  const int m = lane & 15;
  const int grp = lane >> 4;
  _Float16* tp = ldsT[wv];
  const int row_r = lane >> 2;   // epilogue: row 0..15
  const int q_r   = lane & 3;    // epilogue: 8-col quarter

  // B-frag: lane holds W1[k = kb*32 + grp*8 + j][n = 32wv + 16c + m]
  const _Float16* wb0 = w1t + (size_t)(32 * wv + m) * 256 + grp * 8;
  const _Float16* wb1 = wb0 + 16 * 256;
  const half8_t b00 = LDB(wb0, 0),   b01 = LDB(wb0, 32),  b02 = LDB(wb0, 64),
                b03 = LDB(wb0, 96),  b04 = LDB(wb0, 128), b05 = LDB(wb0, 160),
                b06 = LDB(wb0, 192), b07 = LDB(wb0, 224);
  const half8_t b10 = LDB(wb1, 0),   b11 = LDB(wb1, 32),  b12 = LDB(wb1, 64),
                b13 = LDB(wb1, 96),  b14 = LDB(wb1, 128), b15 = LDB(wb1, 160),
                b16 = LDB(wb1, 192), b17 = LDB(wb1, 224);

  const int bid = blockIdx.x - BUILD_GRID;

// issue 4 async 1KB row-loads for this wave (rows wv*4 .. wv*4+3);
// global source chunk = lane ^ (row&7)  (involution; read applies same XOR)
#define STAGE(BUFI, T)                                                         \
  {                                                                            \
    const float* tb = x + (size_t)(T) * 4096;                                  \
    _Pragma("unroll") for (int r = 0; r < 4; ++r) {                            \
      const int mr = wv * 4 + r;                                               \
      const float* srcp = tb + mr * 256 + ((lane ^ (mr & 7)) << 2);            \
      __builtin_amdgcn_global_load_lds(                                        \
          (const __attribute__((address_space(1))) unsigned int*)srcp,         \
          (__attribute__((address_space(3))) unsigned int*)&ldsA[BUFI][mr * 256], \
          16, 0, 0);                                                           \
    }                                                                          \
  }

#define STEP(BUFI, KB, B0, B1)                                                 \
  {                                                                            \
    const int c0 = ((KB * 8 + grp * 2) ^ (m & 7)) << 2;                        \
    const int c1 = ((KB * 8 + grp * 2 + 1) ^ (m & 7)) << 2;                    \
    const f32x4 fa = *reinterpret_cast<const f32x4*>(&ldsA[BUFI][m * 256 + c0]); \
    const f32x4 fb = *reinterpret_cast<const f32x4*>(&ldsA[BUFI][m * 256 + c1]); \
    half8_t af;                                                                \
    af[0] = (_Float16)fa[0]; af[1] = (_Float16)fa[1];                          \
    af[2] = (_Float16)fa[2]; af[3] = (_Float16)fa[3];                          \
    af[4] = (_Float16)fb[0]; af[5] = (_Float16)fb[1];                          \
    af[6] = (_Float16)fb[2]; af[7] = (_Float16)fb[3];                          \
    acc0 = __builtin_amdgcn_mfma_f32_16x16x32_f16(af, B0, acc0, 0, 0, 0);      \
    acc1 = __builtin_amdgcn_mfma_f32_16x16x32_f16(af, B1, acc1, 0, 0, 0);      \
  }

  // prologue: async-stage tile bid into buf 0
  STAGE(0, bid);
  __syncthreads();

  int cur = 0;
  for (int t = bid; t < NT16; t += GEMM_GRID) {
    const int nxt = t + GEMM_GRID;
    // (a) issue next tile's async loads into the other buffer
    if (nxt < NT16) STAGE(cur ^ 1, nxt);
    // (b) compute current tile from LDS (cvt at read; swizzled chunks)
    {
      f32x4 acc0 = {0.f, 0.f, 0.f, 0.f};
      f32x4 acc1 = {0.f, 0.f, 0.f, 0.f};
      STEP(cur, 0, b00, b10)
      STEP(cur, 1, b01, b11)
      STEP(cur, 2, b02, b12)
      STEP(cur, 3, b03, b13)
      STEP(cur, 4, b04, b14)
      STEP(cur, 5, b05, b15)
      STEP(cur, 6, b06, b16)
      STEP(cur, 7, b07, b17)
      // epilogue: wave-private transpose patch -> coalesced g store
#pragma unroll
      for (int r = 0; r < 4; ++r) {
        tp[(4 * grp + r) * 40 + m]      = (_Float16)acc0[r];
        tp[(4 * grp + r) * 40 + 16 + m] = (_Float16)acc1[r];
      }
      const half8_t ov =
          *reinterpret_cast<const half8_t*>(tp + row_r * 40 + q_r * 8);
      *reinterpret_cast<half8_t*>(
          g + ((size_t)t * 16 + row_r) * 128 + 32 * wv + q_r * 8) = ov;
    }
    // (c) one barrier per tile (drains the async loads; m97 pattern)
    __syncthreads();
    cur ^= 1;
  }
#undef STAGE
#undef STEP
}

// ---------------- layer-1 aggregation over g (fp16, 77 MB, L3-resident):
// h1[d] = relu(rsqrt(indeg)*sum ew*rsqrt(outdeg0[src])*g[src] + b1) * rsqrt(outdeg1[d])
__global__ __launch_bounds__(256) void k_gather1(
    const _Float16* __restrict__ g, const int* __restrict__ cnt,
    const int2* __restrict__ edge, const int* __restrict__ outdeg0,
    const int* __restrict__ outdeg1, const float* __restrict__ b1,
    float* __restrict__ h1) {
  const int w = (blockIdx.x * 256 + threadIdx.x) >> 6;  // dst row
  const int lane = threadIdx.x & 63;
  const int gp = lane >> 4;
  const int sl = lane & 15;
  if (w >= ND0) return;
  const int deg = min(cnt[w], SLOTS);
  const int2* ep = edge + (size_t)w * SLOTS;
  float acc[8] = {0.f, 0.f, 0.f, 0.f, 0.f, 0.f, 0.f, 0.f};
  for (int e = 0; e < deg; e += 4) {
    const int idx = e + gp;
    int2 p = make_int2(0, 0);
    float c = 0.f;
    if (idx < deg) {
      p = ep[idx];
      c = __int_as_float(p.y) * rsqrtf(fmaxf((float)outdeg0[p.x], 1.0f));
    }
    const half8_t v =
        *reinterpret_cast<const half8_t*>(g + (size_t)p.x * 128 + sl * 8);
#pragma unroll
    for (int j = 0; j < 8; ++j) acc[j] = fmaf(c, (float)v[j], acc[j]);
  }
#pragma unroll
  for (int j = 0; j < 8; ++j) {
    acc[j] += __shfl_xor(acc[j], 16, 64);
    acc[j] += __shfl_xor(acc[j], 32, 64);
  }
  if (gp == 0) {
    const float sc = rsqrtf(fmaxf((float)deg, 1.0f));
    const float s1 = rsqrtf(fmaxf((float)outdeg1[w], 1.0f));
    const float4 bv0 = *reinterpret_cast<const float4*>(b1 + sl * 8);
    const float4 bv1 = *reinterpret_cast<const float4*>(b1 + sl * 8 + 4);
    float4 o0, o1;
    o0.x = fmaxf(fmaf(acc[0], sc, bv0.x), 0.0f) * s1;
    o0.y = fmaxf(fmaf(acc[1], sc, bv0.y), 0.0f) * s1;
    o0.z = fmaxf(fmaf(acc[2], sc, bv0.z), 0.0f) * s1;
    o0.w = fmaxf(fmaf(acc[3], sc, bv0.w), 0.0f) * s1;
    o1.x = fmaxf(fmaf(acc[4], sc, bv1.x), 0.0f) * s1;
    o1.y = fmaxf(fmaf(acc[5], sc, bv1.y), 0.0f) * s1;
    o1.z = fmaxf(fmaf(acc[6], sc, bv1.z), 0.0f) * s1;
    o1.w = fmaxf(fmaf(acc[7], sc, bv1.w), 0.0f) * s1;
    float* hr = h1 + (size_t)w * 128 + sl * 8;
    *reinterpret_cast<float4*>(hr) = o0;
    *reinterpret_cast<float4*>(hr + 4) = o1;
  }
}

#define FMA2(acc, c, v)        \
  acc.x = fmaf(c, v.x, acc.x); \
  acc.y = fmaf(c, v.y, acc.y);

// --------------------------------------------- fused gather + GEMM, layer 2
__global__ __launch_bounds__(256) void k_layer2(
    const float* __restrict__ h1, const int* __restrict__ cnt,
    const int2* __restrict__ edge, const float* __restrict__ W2,
    const float* __restrict__ b2, float* __restrict__ out) {
  __shared__ float arow[8][HID_F];
  const int t = blockIdx.x;
  const int wv = threadIdx.x >> 6;
  const int lane = threadIdx.x & 63;

#pragma unroll
  for (int rr = 0; rr < 2; ++rr) {
    const int row = t * 8 + wv * 2 + rr;
    const int deg = min(cnt[row], SLOTS);
    const int2* ep = edge + (size_t)row * SLOTS;
    float2 acc = make_float2(0.f, 0.f);
    int e = 0;
    for (; e + 4 <= deg; e += 4) {
      int4 q0 = *reinterpret_cast<const int4*>(ep + e);
      int4 q1 = *reinterpret_cast<const int4*>(ep + e + 2);
      float2 v0 = *reinterpret_cast<const float2*>(h1 + (size_t)q0.x * HID_F + lane * 2);
      float2 v1 = *reinterpret_cast<const float2*>(h1 + (size_t)q0.z * HID_F + lane * 2);
      float2 v2 = *reinterpret_cast<const float2*>(h1 + (size_t)q1.x * HID_F + lane * 2);
      float2 v3 = *reinterpret_cast<const float2*>(h1 + (size_t)q1.z * HID_F + lane * 2);
      FMA2(acc, __int_as_float(q0.y), v0);
      FMA2(acc, __int_as_float(q0.w), v1);
      FMA2(acc, __int_as_float(q1.y), v2);
      FMA2(acc, __int_as_float(q1.w), v3);
    }
    for (; e < deg; ++e) {
      int2 p = ep[e];
      float2 v = *reinterpret_cast<const float2*>(h1 + (size_t)p.x * HID_F + lane * 2);
      FMA2(acc, __int_as_float(p.y), v);
    }
    const float sc = rsqrtf(fmaxf((float)deg, 1.0f));
    *reinterpret_cast<float2*>(&arow[wv * 2 + rr][lane * 2]) =
        make_float2(acc.x * sc, acc.y * sc);
  }
  __syncthreads();

  const int j = threadIdx.x & 127;
  const int rg = threadIdx.x >> 7;
  float a0 = 0.f, a1 = 0.f, a2 = 0.f, a3 = 0.f;
  const float* wj = W2 + j;
#pragma unroll 8
  for (int k = 0; k < HID_F; ++k) {
    const float wvv = wj[(size_t)k * 128];
    a0 = fmaf(arow[rg * 4 + 0][k], wvv, a0);
    a1 = fmaf(arow[rg * 4 + 1][k], wvv, a1);
    a2 = fmaf(arow[rg * 4 + 2][k], wvv, a2);
    a3 = fmaf(arow[rg * 4 + 3][k], wvv, a3);
  }
  const float bj = b2[j];
  const int row0 = t * 8 + rg * 4;
  out[(size_t)(row0 + 0) * 128 + j] = fmaxf(a0 + bj, 0.0f);
  out[(size_t)(row0 + 1) * 128 + j] = fmaxf(a1 + bj, 0.0f);
  out[(size_t)(row0 + 2) * 128 + j] = fmaxf(a2 + bj, 0.0f);
  out[(size_t)(row0 + 3) * 128 + j] = fmaxf(a3 + bj, 0.0f);
}

extern "C" void kernel_launch(void* const* d_in, const int* in_sizes, int n_in,
                              void* d_out, int out_size, void* d_ws, size_t ws_size,
                              hipStream_t stream) {
  const float* x    = (const float*)d_in[0];
  const int*   src0 = (const int*)d_in[1];
  const int*   dst0 = (const int*)d_in[2];
  const float* ew0  = (const float*)d_in[3];
  const int*   src1 = (const int*)d_in[4];
  const int*   dst1 = (const int*)d_in[5];
  const float* ew1  = (const float*)d_in[6];
  const float* W1   = (const float*)d_in[7];
  const float* b1   = (const float*)d_in[8];
  const float* W2   = (const float*)d_in[9];
  const float* b2   = (const float*)d_in[10];
  float* out = (float*)d_out;

  int*   wsi = (int*)d_ws;
  float* wsf = (float*)d_ws;
  int* outdeg0 = wsi + OFF_OUTDEG0I;
  int* outdeg1 = wsi + OFF_OUTDEG1I;
  int* cnt0    = wsi + OFF_CNT0;
  int* cnt1    = wsi + OFF_CNT1;
  int2* edge0  = (int2*)(wsi + OFF_EDGE0);
  int2* edge1  = (int2*)(wsi + OFF_EDGE1);
  float* h1    = wsf + OFF_H1;
  _Float16* w1t = (_Float16*)(wsi + OFF_W1T);
  _Float16* g   = (_Float16*)(wsi + OFF_G);

  k_init<<<160, 256, 0, stream>>>((int4*)d_ws, W1, w1t);
  k_gemm_build<<<BUILD_GRID + GEMM_GRID, 256, 0, stream>>>(
      x, w1t, g, src0, dst0, ew0, outdeg0, cnt0, edge0,
      src1, dst1, ew1, outdeg1, cnt1, edge1);
  k_gather1<<<(ND0 * 64) / 256, 256, 0, stream>>>(g, cnt0, edge0, outdeg0,
                                                  outdeg1, b1, h1);
  k_layer2<<<ND1 / 8, 256, 0, stream>>>(h1, cnt1, edge1, W2, b2, out);
}